// Round 3
// baseline (610.575 us; speedup 1.0000x reference)
//
#include <hip/hip_runtime.h>
#include <cstdint>
#include <cstddef>

#define NOBJ 32
#define NP   992
#define DD   256
#define SP   196   // 14*14
#define OC   151
#define RC   51
#define RED  64
#define KIN  4251  // 4096 + 151 + 4
#define CH   128   // emb1 k-chunks
#define KPC  34    // ceil(4251/128)

// ---- ws layout (float offsets) ----
#define OFF_PART   0u         // 128*32*256 = 1048576
#define OFF_OBJF   1048576u   // 8192
#define OFF_SALL   1056768u   // 992*768 = 761856
#define OFF_RELF   1818624u   // 253952
#define OFF_H      2072576u   // 262144
#define OFF_W2T    2334720u   // 65536
#define OFF_WC1T   2400256u   // 196608
#define OFF_WC2T   2596864u   // 65536
#define OFF_WGT    2662400u   // 65536
#define OFF_FC1WT  2727936u   // 49152
#define OFF_FC2WT  2777088u   // 49152
#define OFF_WOPT   2826240u   // 38656
#define OFF_WRPT   2864896u   // 13056
// total 2877952 floats = 11.5 MB

#define TR_TOT 543232  // total transposed elements

// ============ K_PRE: union(0..991) + emb1(992..1119) + transpose(1120..1375)
__global__ void k_pre(const float* __restrict__ uf,
                      const float* __restrict__ bbox,
                      const int* __restrict__ pairs,
                      const float* __restrict__ roi,
                      const float* __restrict__ logits,
                      const float* __restrict__ W1,
                      const float* __restrict__ W2,  const float* __restrict__ Wc1,
                      const float* __restrict__ Wc2, const float* __restrict__ Wg,
                      const float* __restrict__ f1w, const float* __restrict__ f2w,
                      const float* __restrict__ Wop, const float* __restrict__ Wrp,
                      float* __restrict__ sAll, float* __restrict__ part,
                      float* __restrict__ W2T,  float* __restrict__ Wc1T,
                      float* __restrict__ Wc2T, float* __restrict__ WgT,
                      float* __restrict__ f1wT, float* __restrict__ f2wT,
                      float* __restrict__ WopT, float* __restrict__ WrpT) {
  const int b = blockIdx.x, t = threadIdx.x;
  if (b < NP) {
    // ---- union masked means ----
    const int p = b;
    __shared__ __align__(16) float wS[SP];
    __shared__ __align__(16) float wO[SP];
    __shared__ __align__(16) float wB[SP];
    if (t < SP) {
      int si = pairs[2 * p], oi = pairs[2 * p + 1];
      float sx1 = bbox[si * 4 + 0], sy1 = bbox[si * 4 + 1];
      float sx2 = bbox[si * 4 + 2], sy2 = bbox[si * 4 + 3];
      float ox1 = bbox[oi * 4 + 0], oy1 = bbox[oi * 4 + 1];
      float ox2 = bbox[oi * 4 + 2], oy2 = bbox[oi * 4 + 3];
      float ux = fminf(sx1, ox1), uy = fminf(sy1, oy1);
      float xr = 14.f / fmaxf(sx2 - ux, ox2 - ux);
      float yr = 14.f / fmaxf(sy2 - uy, oy2 - uy);
      float xs0 = rintf((sx1 - ux) * xr), xs1 = rintf((sx2 - ux) * xr);
      float xo0 = rintf((ox1 - ux) * xr), xo1 = rintf((ox2 - ux) * xr);
      float ys0 = rintf((sy1 - uy) * yr), ys1 = rintf((sy2 - uy) * yr);
      float yo0 = rintf((oy1 - uy) * yr), yo1 = rintf((oy2 - uy) * yr);
      int a = t / 14, bb = t - a * 14;
      float fa = (float)a, fb = (float)bb;
      float sm = (fa >= xs0 && fa < xs1 && fb >= ys0 && fb < ys1) ? 1.f : 0.f;
      float om = (fa >= xo0 && fa < xo1 && fb >= yo0 && fb < yo1) ? 1.f : 0.f;
      float bm = fminf(fmaxf(1.f - sm - om, 0.f), 1.f);
      wS[t] = sm; wO[t] = om; wB[t] = bm;
    }
    __syncthreads();
    const float4* u4 = (const float4*)(uf + ((size_t)p * DD + t) * SP);
    float as0 = 0, as1 = 0, ao0 = 0, ao1 = 0, ab0 = 0, ab1 = 0;
#pragma unroll 7
    for (int j = 0; j < SP / 4; ++j) {
      float4 v  = u4[j];
      float4 ms = *(const float4*)&wS[4 * j];
      float4 mo = *(const float4*)&wO[4 * j];
      float4 mb = *(const float4*)&wB[4 * j];
      as0 += v.x * ms.x + v.y * ms.y;  as1 += v.z * ms.z + v.w * ms.w;
      ao0 += v.x * mo.x + v.y * mo.y;  ao1 += v.z * mo.z + v.w * mo.w;
      ab0 += v.x * mb.x + v.y * mb.y;  ab1 += v.z * mb.z + v.w * mb.w;
    }
    const float inv = 1.f / 196.f;
    float* o = sAll + (size_t)p * 768;
    o[t]       = (as0 + as1) * inv;
    o[256 + t] = (ao0 + ao1) * inv;
    o[512 + t] = (ab0 + ab1) * inv;
  } else if (b < NP + CH) {
    // ---- emb1 split-K partial ----
    const int chunk = b - NP;
    int k0 = chunk * KPC;
    int k1 = k0 + KPC; if (k1 > KIN) k1 = KIN;
    float acc[NOBJ];
#pragma unroll
    for (int i = 0; i < NOBJ; ++i) acc[i] = 0.f;
#pragma unroll 2
    for (int k = k0; k < k1; ++k) {
      float w = W1[(size_t)k * DD + t];
      const float* xp; int stride;
      if (k < 4096)            { xp = roi    + k;               stride = 4096; }
      else if (k < 4096 + OC)  { xp = logits + (k - 4096);      stride = OC;   }
      else                     { xp = bbox   + (k - 4096 - OC); stride = 4;    }
#pragma unroll
      for (int i = 0; i < NOBJ; ++i) { acc[i] += xp[0] * w; xp += stride; }
    }
    float* pout = part + (size_t)chunk * (NOBJ * DD) + t;
#pragma unroll
    for (int i = 0; i < NOBJ; ++i) pout[i * DD] = acc[i];
  } else {
    // ---- weight transposes: coalesced writes, strided (L2-hit) reads ----
    for (int o = (b - NP - CH) * 256 + t; o < TR_TOT; o += 256 * 256) {
      float v; float* dst;
      if (o < 65536)       { int q = o;          v = W2 [(q & 255) * 256 + (q >> 8)]; dst = W2T  + q; }
      else if (o < 262144) { int q = o - 65536;  int c = q / 768, k = q - c * 768;
                             v = Wc1[k * 256 + c];                                    dst = Wc1T + q; }
      else if (o < 327680) { int q = o - 262144; v = Wc2[(q & 255) * 256 + (q >> 8)]; dst = Wc2T + q; }
      else if (o < 393216) { int q = o - 327680; v = Wg [(q & 255) * 256 + (q >> 8)]; dst = WgT  + q; }
      else if (o < 442368) { int q = o - 393216;
                             v = f1w[(q >> 14) * 16384 + (q & 255) * 64 + ((q >> 8) & 63)];
                             dst = f1wT + q; }
      else if (o < 491520) { int q = o - 442368;
                             v = f2w[(q >> 14) * 16384 + (q & 63) * 256 + ((q >> 6) & 255)];
                             dst = f2wT + q; }
      else if (o < 530176) { int q = o - 491520; v = Wop[(q & 255) * OC + (q >> 8)];  dst = WopT + q; }
      else                 { int q = o - 530176; v = Wrp[(q & 255) * RC + (q >> 8)];  dst = WrpT + q; }
      *dst = v;
    }
  }
}

// ============ K_MID: attrel(0..247) + emb2(248..255), 1024 threads =========
__global__ void __launch_bounds__(1024, 1)
k_mid(const float* __restrict__ sAll,
      const float* __restrict__ f1wT, const float* __restrict__ f1b,
      const float* __restrict__ f2wT, const float* __restrict__ f2b,
      const float* __restrict__ Wc1T, const float* __restrict__ bc1,
      const float* __restrict__ Wc2T, const float* __restrict__ bc2,
      const float* __restrict__ part, const float* __restrict__ b1,
      const float* __restrict__ W2T,  const float* __restrict__ b2,
      float* __restrict__ relf, float* __restrict__ objf) {
  const int b = blockIdx.x, t = threadIdx.x;
  const int p = t >> 8, tt = t & 255;
  __shared__ __align__(16) float sg[4][768];
  __shared__ __align__(16) float ha[4][192];
  __shared__ __align__(16) float h2[4][256];
  if (b < NP / 4) {
    const int p0 = b * 4;
    // stage 4 pair-rows
    {
      const float4* src = (const float4*)(sAll + (size_t)p0 * 768);
      float4* dst = (float4*)&sg[0][0];
      if (t < 768) dst[t] = src[t];
    }
    __syncthreads();
    // phase 1: fc1 — thread (p, tt<192)
    if (tt < 192) {
      const int br = tt >> 6, c = tt & 63;
      const float4* w4 = (const float4*)(f1wT + (br * 64 + c) * 256);
      const float* sp = &sg[p][br * 256];
      float a0 = 0, a1 = 0, a2 = 0, a3 = 0;
#pragma unroll 8
      for (int j = 0; j < 64; ++j) {
        float4 wv = w4[j];
        float4 sv = *(const float4*)&sp[4 * j];
        a0 += sv.x * wv.x; a1 += sv.y * wv.y; a2 += sv.z * wv.z; a3 += sv.w * wv.w;
      }
      ha[p][tt] = fmaxf((a0 + a1) + (a2 + a3) + f1b[br * 64 + c], 0.f);
    }
    __syncthreads();
    // phase 2: fc2 + sigmoid gate — thread (p, tt), 3 branches
#pragma unroll
    for (int br = 0; br < 3; ++br) {
      const float4* w4 = (const float4*)(f2wT + br * 16384 + tt * 64);
      const float* hp = &ha[p][br * 64];
      float a0 = 0, a1 = 0, a2 = 0, a3 = 0;
#pragma unroll
      for (int j = 0; j < 16; ++j) {
        float4 wv = w4[j];
        float4 hv = *(const float4*)&hp[4 * j];
        a0 += hv.x * wv.x; a1 += hv.y * wv.y; a2 += hv.z * wv.z; a3 += hv.w * wv.w;
      }
      float g = 1.f / (1.f + expf(-((a0 + a1) + (a2 + a3) + f2b[br * 256 + tt])));
      sg[p][br * 256 + tt] *= g;
    }
    __syncthreads();
    // phase 3: rel fc1 768->256 relu — thread (p, tt)
    {
      const float4* w4 = (const float4*)(Wc1T + (size_t)tt * 768);
      const float* gp = &sg[p][0];
      float a0 = 0, a1 = 0, a2 = 0, a3 = 0;
#pragma unroll 8
      for (int j = 0; j < 192; ++j) {
        float4 wv = w4[j];
        float4 gv = *(const float4*)&gp[4 * j];
        a0 += gv.x * wv.x; a1 += gv.y * wv.y; a2 += gv.z * wv.z; a3 += gv.w * wv.w;
      }
      h2[p][tt] = fmaxf((a0 + a1) + (a2 + a3) + bc1[tt], 0.f);
    }
    __syncthreads();
    // phase 4: rel fc2 256->256 — thread (p, tt)
    {
      const float4* w4 = (const float4*)(Wc2T + (size_t)tt * 256);
      const float* hp = &h2[p][0];
      float a0 = 0, a1 = 0, a2 = 0, a3 = 0;
#pragma unroll 8
      for (int j = 0; j < 64; ++j) {
        float4 wv = w4[j];
        float4 hv = *(const float4*)&hp[4 * j];
        a0 += hv.x * wv.x; a1 += hv.y * wv.y; a2 += hv.z * wv.z; a3 += hv.w * wv.w;
      }
      relf[(size_t)(p0 + p) * DD + tt] = (a0 + a1) + (a2 + a3) + bc2[tt];
    }
  } else {
    // ---- emb2: rows r = (b-248)*4 + p ----
    const int r = (b - NP / 4) * 4 + p;   // 0..31
    float s[8];
#pragma unroll
    for (int u = 0; u < 8; ++u) s[u] = 0.f;
#pragma unroll
    for (int c0 = 0; c0 < CH; c0 += 8) {
#pragma unroll
      for (int u = 0; u < 8; ++u)
        s[u] += part[(size_t)(c0 + u) * (NOBJ * DD) + r * DD + tt];
    }
    float tot = ((s[0] + s[1]) + (s[2] + s[3])) + ((s[4] + s[5]) + (s[6] + s[7]));
    h2[p][tt] = fmaxf(tot + b1[tt], 0.f);
    __syncthreads();
    const float4* w4 = (const float4*)(W2T + (size_t)tt * DD);
    const float* hp = &h2[p][0];
    float a0 = 0, a1 = 0, a2 = 0, a3 = 0;
#pragma unroll 8
    for (int j = 0; j < 64; ++j) {
      float4 wv = w4[j];
      float4 hv = *(const float4*)&hp[4 * j];
      a0 += hv.x * wv.x; a1 += hv.y * wv.y; a2 += hv.z * wv.z; a3 += hv.w * wv.w;
    }
    objf[r * DD + tt] = (a0 + a1) + (a2 + a3) + b2[tt];
  }
}

// ============ K_GCNH: H = concat(objf, relf) @ Wg (2 rows / block) =========
__global__ void k_gcn_h(const float* __restrict__ objf, const float* __restrict__ relf,
                        const float* __restrict__ WgT, float* __restrict__ H) {
  const int r0 = blockIdx.x * 2;
  const int t = threadIdx.x;
  __shared__ __align__(16) float fin[2][DD];
#pragma unroll
  for (int r = 0; r < 2; ++r) {
    int row = r0 + r;
    fin[r][t] = (row < NOBJ) ? objf[row * DD + t]
                             : relf[(size_t)(row - NOBJ) * DD + t];
  }
  __syncthreads();
  const float4* w4 = (const float4*)(WgT + (size_t)t * DD);
  float a0 = 0, a1 = 0;
#pragma unroll 8
  for (int j = 0; j < DD / 4; ++j) {
    float4 wv = w4[j];
    float4 f0 = *(const float4*)&fin[0][4 * j];
    float4 f1 = *(const float4*)&fin[1][4 * j];
    a0 += f0.x * wv.x + f0.y * wv.y + f0.z * wv.z + f0.w * wv.w;
    a1 += f1.x * wv.x + f1.y * wv.y + f1.z * wv.z + f1.w * wv.w;
  }
  H[(size_t)(r0 + 0) * DD + t] = a0;
  H[(size_t)(r0 + 1) * DD + t] = a1;
}

// ============ K_HEADS: rel(0..247, 4 pairs) + obj(248..279), 1024 thr ======
__global__ void __launch_bounds__(1024, 1)
k_heads(const float* __restrict__ H, const float* __restrict__ objf,
        const float* __restrict__ relf, const int* __restrict__ pairs,
        const float* __restrict__ bg,
        const float* __restrict__ WopT, const float* __restrict__ bop,
        const float* __restrict__ WrpT, const float* __restrict__ brp,
        float* __restrict__ out) {
  const int b = blockIdx.x, t = threadIdx.x;
  const int p = t >> 8, tt = t & 255;
  if (b < NP / 4) {
    __shared__ __align__(16) float gr[4][DD];
    __shared__ float red[4][4][64];
    const int r = b * 4 + p;
    int si = pairs[2 * r], oi = pairs[2 * r + 1];
    float hsum = H[si * DD + tt] + H[oi * DD + tt] + H[(size_t)(NOBJ + r) * DD + tt];
    gr[p][tt] = fmaxf(hsum * (1.f / 3.f) + bg[tt], 0.f) + relf[(size_t)r * DD + tt];
    __syncthreads();
    const int q = tt >> 6, c = tt & 63;
    float a = 0.f;
    if (c < RC) {
      const float4* w4 = (const float4*)(WrpT + c * 256 + q * 64);
#pragma unroll
      for (int j = 0; j < 16; ++j) {
        float4 wv = w4[j];
        float4 gv = *(const float4*)&gr[p][q * 64 + 4 * j];
        a += gv.x * wv.x + gv.y * wv.y + gv.z * wv.z + gv.w * wv.w;
      }
    }
    red[p][q][c] = a;
    __syncthreads();
    if (tt < RC)
      out[NOBJ * OC + (size_t)r * RC + tt] =
          red[p][0][tt] + red[p][1][tt] + red[p][2][tt] + red[p][3][tt] + brp[tt];
  } else {
    const int i = b - NP / 4;   // 0..31
    const int slice = p;
    __shared__ int2 pr[NP];
    __shared__ float red2[4][DD];
    __shared__ __align__(16) float gro[DD];
    const int2* p2 = (const int2*)pairs;
    for (int r = t; r < NP; r += 1024) pr[r] = p2[r];
    __syncthreads();
    float acc = 0.f;
    if (slice == 0) {
#pragma unroll 8
      for (int j = 0; j < NOBJ; ++j) acc += H[j * DD + tt];
    }
    const int rbeg = slice * 248;
#pragma unroll 8
    for (int r = rbeg; r < rbeg + 248; ++r) {
      int2 q = pr[r];
      float v = H[(size_t)(NOBJ + r) * DD + tt];
      if (q.x == i || q.y == i) acc += v;
    }
    red2[slice][tt] = acc;
    __syncthreads();
    if (t < DD) {
      float pre = (red2[0][t] + red2[1][t] + red2[2][t] + red2[3][t]) * (1.f / 94.f);
      gro[t] = fmaxf(pre + bg[t], 0.f) + objf[i * DD + t];
    }
    __syncthreads();
    float hsum = 0.f;
    if (tt < OC) {
      const float4* w4 = (const float4*)(WopT + tt * 256 + slice * 64);
#pragma unroll
      for (int j = 0; j < 16; ++j) {
        float4 wv = w4[j];
        float4 gv = *(const float4*)&gro[slice * 64 + 4 * j];
        hsum += gv.x * wv.x + gv.y * wv.y + gv.z * wv.z + gv.w * wv.w;
      }
    }
    red2[slice][tt] = hsum;
    __syncthreads();
    if (t < OC)
      out[i * OC + t] = red2[0][t] + red2[1][t] + red2[2][t] + red2[3][t] + bop[t];
  }
}

extern "C" void kernel_launch(void* const* d_in, const int* in_sizes, int n_in,
                              void* d_out, int out_size, void* d_ws, size_t ws_size,
                              hipStream_t stream) {
  const float* roi   = (const float*)d_in[0];
  const float* bbox  = (const float*)d_in[1];
  const float* logit = (const float*)d_in[2];
  const float* uf    = (const float*)d_in[3];
  const int*   pairs = (const int*)d_in[4];
  const float* W1    = (const float*)d_in[5];
  const float* b1    = (const float*)d_in[6];
  const float* W2    = (const float*)d_in[7];
  const float* b2    = (const float*)d_in[8];
  const float* fc1w  = (const float*)d_in[9];
  const float* fc1b  = (const float*)d_in[10];
  const float* fc2w  = (const float*)d_in[11];
  const float* fc2b  = (const float*)d_in[12];
  const float* Wc1   = (const float*)d_in[13];
  const float* bc1   = (const float*)d_in[14];
  const float* Wc2   = (const float*)d_in[15];
  const float* bc2   = (const float*)d_in[16];
  const float* Wg    = (const float*)d_in[17];
  const float* bg    = (const float*)d_in[18];
  const float* Wop   = (const float*)d_in[19];
  const float* bop   = (const float*)d_in[20];
  const float* Wrp   = (const float*)d_in[21];
  const float* brp   = (const float*)d_in[22];

  float* ws    = (float*)d_ws;
  float* part  = ws + OFF_PART;
  float* objf  = ws + OFF_OBJF;
  float* sAll  = ws + OFF_SALL;
  float* relf  = ws + OFF_RELF;
  float* Hbuf  = ws + OFF_H;
  float* W2T   = ws + OFF_W2T;
  float* Wc1T  = ws + OFF_WC1T;
  float* Wc2T  = ws + OFF_WC2T;
  float* WgT   = ws + OFF_WGT;
  float* f1wT  = ws + OFF_FC1WT;
  float* f2wT  = ws + OFF_FC2WT;
  float* WopT  = ws + OFF_WOPT;
  float* WrpT  = ws + OFF_WRPT;
  float* out   = (float*)d_out;

  k_pre<<<NP + CH + 256, 256, 0, stream>>>(uf, bbox, pairs, roi, logit, W1,
                                           W2, Wc1, Wc2, Wg, fc1w, fc2w, Wop, Wrp,
                                           sAll, part, W2T, Wc1T, Wc2T, WgT,
                                           f1wT, f2wT, WopT, WrpT);
  k_mid<<<NP / 4 + 8, 1024, 0, stream>>>(sAll, f1wT, fc1b, f2wT, fc2b,
                                         Wc1T, bc1, Wc2T, bc2,
                                         part, b1, W2T, b2, relf, objf);
  k_gcn_h<<<(NOBJ + NP) / 2, 256, 0, stream>>>(objf, relf, WgT, Hbuf);
  k_heads<<<NP / 4 + NOBJ, 1024, 0, stream>>>(Hbuf, objf, relf, pairs, bg,
                                              WopT, bop, WrpT, brp, out);
}

// Round 4
// 525.895 us; speedup vs baseline: 1.1610x; 1.1610x over previous
//
#include <hip/hip_runtime.h>
#include <cstdint>
#include <cstddef>

#define NOBJ 32
#define NP   992
#define DD   256
#define SP   196   // 14*14
#define OC   151
#define RC   51
#define RED  64
#define KIN  4251  // 4096 + 151 + 4
#define CH   128   // emb1 k-chunks
#define KPC  34    // ceil(4251/128)

// ---- ws layout (float offsets) ----
#define OFF_PART   0u         // 128*32*256 = 1048576
#define OFF_OBJF   1048576u   // 8192
#define OFF_SALL   1056768u   // 992*768 = 761856
#define OFF_RELF   1818624u   // 253952
#define OFF_H      2072576u   // 262144
#define OFF_W2T    2334720u   // 65536
#define OFF_WC1T   2400256u   // 196608
#define OFF_WC2T   2596864u   // 65536
#define OFF_WGT    2662400u   // 65536
#define OFF_FC1WT  2727936u   // 49152
#define OFF_FC2WT  2777088u   // 49152
#define OFF_WOPT   2826240u   // 38656
#define OFF_WRPT   2864896u   // 13056

#define TR_TOT 543232  // total transposed elements

// ============ K_PRE: union(0..991) + emb1(992..1119) + transpose(1120..1375)
__global__ void k_pre(const float* __restrict__ uf,
                      const float* __restrict__ bbox,
                      const int* __restrict__ pairs,
                      const float* __restrict__ roi,
                      const float* __restrict__ logits,
                      const float* __restrict__ W1,
                      const float* __restrict__ W2,  const float* __restrict__ Wc1,
                      const float* __restrict__ Wc2, const float* __restrict__ Wg,
                      const float* __restrict__ f1w, const float* __restrict__ f2w,
                      const float* __restrict__ Wop, const float* __restrict__ Wrp,
                      float* __restrict__ sAll, float* __restrict__ part,
                      float* __restrict__ W2T,  float* __restrict__ Wc1T,
                      float* __restrict__ Wc2T, float* __restrict__ WgT,
                      float* __restrict__ f1wT, float* __restrict__ f2wT,
                      float* __restrict__ WopT, float* __restrict__ WrpT) {
  const int b = blockIdx.x, t = threadIdx.x;
  if (b < NP) {
    // ---- union masked means ----
    const int p = b;
    __shared__ __align__(16) float wS[SP];
    __shared__ __align__(16) float wO[SP];
    __shared__ __align__(16) float wB[SP];
    if (t < SP) {
      int si = pairs[2 * p], oi = pairs[2 * p + 1];
      float sx1 = bbox[si * 4 + 0], sy1 = bbox[si * 4 + 1];
      float sx2 = bbox[si * 4 + 2], sy2 = bbox[si * 4 + 3];
      float ox1 = bbox[oi * 4 + 0], oy1 = bbox[oi * 4 + 1];
      float ox2 = bbox[oi * 4 + 2], oy2 = bbox[oi * 4 + 3];
      float ux = fminf(sx1, ox1), uy = fminf(sy1, oy1);
      float xr = 14.f / fmaxf(sx2 - ux, ox2 - ux);
      float yr = 14.f / fmaxf(sy2 - uy, oy2 - uy);
      float xs0 = rintf((sx1 - ux) * xr), xs1 = rintf((sx2 - ux) * xr);
      float xo0 = rintf((ox1 - ux) * xr), xo1 = rintf((ox2 - ux) * xr);
      float ys0 = rintf((sy1 - uy) * yr), ys1 = rintf((sy2 - uy) * yr);
      float yo0 = rintf((oy1 - uy) * yr), yo1 = rintf((oy2 - uy) * yr);
      int a = t / 14, bb = t - a * 14;
      float fa = (float)a, fb = (float)bb;
      float sm = (fa >= xs0 && fa < xs1 && fb >= ys0 && fb < ys1) ? 1.f : 0.f;
      float om = (fa >= xo0 && fa < xo1 && fb >= yo0 && fb < yo1) ? 1.f : 0.f;
      float bm = fminf(fmaxf(1.f - sm - om, 0.f), 1.f);
      wS[t] = sm; wO[t] = om; wB[t] = bm;
    }
    __syncthreads();
    const float4* u4 = (const float4*)(uf + ((size_t)p * DD + t) * SP);
    float as0 = 0, as1 = 0, ao0 = 0, ao1 = 0, ab0 = 0, ab1 = 0;
#pragma unroll 7
    for (int j = 0; j < SP / 4; ++j) {
      float4 v  = u4[j];
      float4 ms = *(const float4*)&wS[4 * j];
      float4 mo = *(const float4*)&wO[4 * j];
      float4 mb = *(const float4*)&wB[4 * j];
      as0 += v.x * ms.x + v.y * ms.y;  as1 += v.z * ms.z + v.w * ms.w;
      ao0 += v.x * mo.x + v.y * mo.y;  ao1 += v.z * mo.z + v.w * mo.w;
      ab0 += v.x * mb.x + v.y * mb.y;  ab1 += v.z * mb.z + v.w * mb.w;
    }
    const float inv = 1.f / 196.f;
    float* o = sAll + (size_t)p * 768;
    o[t]       = (as0 + as1) * inv;
    o[256 + t] = (ao0 + ao1) * inv;
    o[512 + t] = (ab0 + ab1) * inv;
  } else if (b < NP + CH) {
    // ---- emb1 split-K partial ----
    const int chunk = b - NP;
    int k0 = chunk * KPC;
    int k1 = k0 + KPC; if (k1 > KIN) k1 = KIN;
    float acc[NOBJ];
#pragma unroll
    for (int i = 0; i < NOBJ; ++i) acc[i] = 0.f;
#pragma unroll 2
    for (int k = k0; k < k1; ++k) {
      float w = W1[(size_t)k * DD + t];
      const float* xp; int stride;
      if (k < 4096)            { xp = roi    + k;               stride = 4096; }
      else if (k < 4096 + OC)  { xp = logits + (k - 4096);      stride = OC;   }
      else                     { xp = bbox   + (k - 4096 - OC); stride = 4;    }
#pragma unroll
      for (int i = 0; i < NOBJ; ++i) { acc[i] += xp[0] * w; xp += stride; }
    }
    float* pout = part + (size_t)chunk * (NOBJ * DD) + t;
#pragma unroll
    for (int i = 0; i < NOBJ; ++i) pout[i * DD] = acc[i];
  } else {
    // ---- weight transposes: coalesced writes, strided (L2-hit) reads ----
    for (int o = (b - NP - CH) * 256 + t; o < TR_TOT; o += 256 * 256) {
      float v; float* dst;
      if (o < 65536)       { int q = o;          v = W2 [(q & 255) * 256 + (q >> 8)]; dst = W2T  + q; }
      else if (o < 262144) { int q = o - 65536;  int c = q / 768, k = q - c * 768;
                             v = Wc1[k * 256 + c];                                    dst = Wc1T + q; }
      else if (o < 327680) { int q = o - 262144; v = Wc2[(q & 255) * 256 + (q >> 8)]; dst = Wc2T + q; }
      else if (o < 393216) { int q = o - 327680; v = Wg [(q & 255) * 256 + (q >> 8)]; dst = WgT  + q; }
      else if (o < 442368) { int q = o - 393216;
                             v = f1w[(q >> 14) * 16384 + (q & 255) * 64 + ((q >> 8) & 63)];
                             dst = f1wT + q; }
      else if (o < 491520) { int q = o - 442368;
                             v = f2w[(q >> 14) * 16384 + (q & 63) * 256 + ((q >> 6) & 255)];
                             dst = f2wT + q; }
      else if (o < 530176) { int q = o - 491520; v = Wop[(q & 255) * OC + (q >> 8)];  dst = WopT + q; }
      else                 { int q = o - 530176; v = Wrp[(q & 255) * RC + (q >> 8)];  dst = WrpT + q; }
      *dst = v;
    }
  }
}

// ============ K_MID2: attrel w/ K-split x2 + H fusion; emb2 + H fusion =====
// blocks 0..247: 4 pairs each, 512 threads (h = K-half, tt = out col)
// blocks 248..263: emb2, 2 obj rows each (h = row), + H_obj
__global__ void __launch_bounds__(512, 1)
k_mid2(const float* __restrict__ sAll,
       const float* __restrict__ f1wT, const float* __restrict__ f1b,
       const float* __restrict__ f2wT, const float* __restrict__ f2b,
       const float* __restrict__ Wc1T, const float* __restrict__ bc1,
       const float* __restrict__ Wc2T, const float* __restrict__ bc2,
       const float* __restrict__ WgT,
       const float* __restrict__ part, const float* __restrict__ b1,
       const float* __restrict__ W2T,  const float* __restrict__ b2,
       float* __restrict__ relf, float* __restrict__ objf,
       float* __restrict__ H) {
  const int b = blockIdx.x, t = threadIdx.x;
  const int h = t >> 8, tt = t & 255;
  __shared__ __align__(16) float sg[4][768];
  __shared__ __align__(16) float ha[4][192];
  __shared__ __align__(16) float h2[4][256];
  __shared__ __align__(16) float red[2][4][256];
  if (b < NP / 4) {
    const int p0 = b * 4;
    // stage 4 pair-rows into LDS
    {
      const float4* src = (const float4*)(sAll + (size_t)p0 * 768);
      float4* dst = (float4*)&sg[0][0];
      for (int j = t; j < 768; j += 512) dst[j] = src[j];
    }
    __syncthreads();
    // ---- P1: fc1 (cols tt<192, K=256 split 128 by h) ----
    if (tt < 192) {
      const float4* w4 = (const float4*)(f1wT + tt * 256 + h * 128);
      const int sb = (tt >> 6) * 256 + h * 128;
      float a0 = 0, a1 = 0, a2 = 0, a3 = 0;
#pragma unroll 8
      for (int j = 0; j < 32; ++j) {
        float4 wv = w4[j];
        float4 s0 = *(const float4*)&sg[0][sb + 4 * j];
        float4 s1 = *(const float4*)&sg[1][sb + 4 * j];
        float4 s2 = *(const float4*)&sg[2][sb + 4 * j];
        float4 s3 = *(const float4*)&sg[3][sb + 4 * j];
        a0 += s0.x * wv.x + s0.y * wv.y + s0.z * wv.z + s0.w * wv.w;
        a1 += s1.x * wv.x + s1.y * wv.y + s1.z * wv.z + s1.w * wv.w;
        a2 += s2.x * wv.x + s2.y * wv.y + s2.z * wv.z + s2.w * wv.w;
        a3 += s3.x * wv.x + s3.y * wv.y + s3.z * wv.z + s3.w * wv.w;
      }
      red[h][0][tt] = a0; red[h][1][tt] = a1; red[h][2][tt] = a2; red[h][3][tt] = a3;
    }
    __syncthreads();
    if (h == 0 && tt < 192) {
      float bb = f1b[tt];
#pragma unroll
      for (int p = 0; p < 4; ++p)
        ha[p][tt] = fmaxf(red[0][p][tt] + red[1][p][tt] + bb, 0.f);
    }
    __syncthreads();
    // ---- P2: fc2 + sigmoid gate (3 branches, K=64 split 32 by h) ----
    for (int br = 0; br < 3; ++br) {
      const float4* w4 = (const float4*)(f2wT + br * 16384 + tt * 64 + h * 32);
      const int hb = br * 64 + h * 32;
      float a0 = 0, a1 = 0, a2 = 0, a3 = 0;
#pragma unroll
      for (int j = 0; j < 8; ++j) {
        float4 wv = w4[j];
        float4 v0 = *(const float4*)&ha[0][hb + 4 * j];
        float4 v1 = *(const float4*)&ha[1][hb + 4 * j];
        float4 v2 = *(const float4*)&ha[2][hb + 4 * j];
        float4 v3 = *(const float4*)&ha[3][hb + 4 * j];
        a0 += v0.x * wv.x + v0.y * wv.y + v0.z * wv.z + v0.w * wv.w;
        a1 += v1.x * wv.x + v1.y * wv.y + v1.z * wv.z + v1.w * wv.w;
        a2 += v2.x * wv.x + v2.y * wv.y + v2.z * wv.z + v2.w * wv.w;
        a3 += v3.x * wv.x + v3.y * wv.y + v3.z * wv.z + v3.w * wv.w;
      }
      red[h][0][tt] = a0; red[h][1][tt] = a1; red[h][2][tt] = a2; red[h][3][tt] = a3;
      __syncthreads();
      if (h == 0) {
        float bb = f2b[br * 256 + tt];
#pragma unroll
        for (int p = 0; p < 4; ++p) {
          float g = 1.f / (1.f + expf(-(red[0][p][tt] + red[1][p][tt] + bb)));
          sg[p][br * 256 + tt] *= g;
        }
      }
      __syncthreads();
    }
    // ---- P3: rel fc1 768->256 relu (K=768 split 384 by h) ----
    {
      const float4* w4 = (const float4*)(Wc1T + (size_t)tt * 768 + h * 384);
      const int gb = h * 384;
      float a0 = 0, a1 = 0, a2 = 0, a3 = 0;
#pragma unroll 8
      for (int j = 0; j < 96; ++j) {
        float4 wv = w4[j];
        float4 g0 = *(const float4*)&sg[0][gb + 4 * j];
        float4 g1 = *(const float4*)&sg[1][gb + 4 * j];
        float4 g2 = *(const float4*)&sg[2][gb + 4 * j];
        float4 g3 = *(const float4*)&sg[3][gb + 4 * j];
        a0 += g0.x * wv.x + g0.y * wv.y + g0.z * wv.z + g0.w * wv.w;
        a1 += g1.x * wv.x + g1.y * wv.y + g1.z * wv.z + g1.w * wv.w;
        a2 += g2.x * wv.x + g2.y * wv.y + g2.z * wv.z + g2.w * wv.w;
        a3 += g3.x * wv.x + g3.y * wv.y + g3.z * wv.z + g3.w * wv.w;
      }
      red[h][0][tt] = a0; red[h][1][tt] = a1; red[h][2][tt] = a2; red[h][3][tt] = a3;
    }
    __syncthreads();
    if (h == 0) {
      float bb = bc1[tt];
#pragma unroll
      for (int p = 0; p < 4; ++p)
        h2[p][tt] = fmaxf(red[0][p][tt] + red[1][p][tt] + bb, 0.f);
    }
    __syncthreads();
    // ---- P4: rel fc2 256->256 (K split 128) -> relf, stash in sg[p][0..255]
    {
      const float4* w4 = (const float4*)(Wc2T + (size_t)tt * 256 + h * 128);
      const int hb = h * 128;
      float a0 = 0, a1 = 0, a2 = 0, a3 = 0;
#pragma unroll 8
      for (int j = 0; j < 32; ++j) {
        float4 wv = w4[j];
        float4 v0 = *(const float4*)&h2[0][hb + 4 * j];
        float4 v1 = *(const float4*)&h2[1][hb + 4 * j];
        float4 v2 = *(const float4*)&h2[2][hb + 4 * j];
        float4 v3 = *(const float4*)&h2[3][hb + 4 * j];
        a0 += v0.x * wv.x + v0.y * wv.y + v0.z * wv.z + v0.w * wv.w;
        a1 += v1.x * wv.x + v1.y * wv.y + v1.z * wv.z + v1.w * wv.w;
        a2 += v2.x * wv.x + v2.y * wv.y + v2.z * wv.z + v2.w * wv.w;
        a3 += v3.x * wv.x + v3.y * wv.y + v3.z * wv.z + v3.w * wv.w;
      }
      red[h][0][tt] = a0; red[h][1][tt] = a1; red[h][2][tt] = a2; red[h][3][tt] = a3;
    }
    __syncthreads();
    if (h == 0) {
      float bb = bc2[tt];
#pragma unroll
      for (int p = 0; p < 4; ++p) {
        float v = red[0][p][tt] + red[1][p][tt] + bb;
        relf[(size_t)(p0 + p) * DD + tt] = v;
        sg[p][tt] = v;     // reuse sg as relf stash for P5
      }
    }
    __syncthreads();
    // ---- P5: H_rel = relf @ Wg (K=256 split 128) ----
    {
      const float4* w4 = (const float4*)(WgT + (size_t)tt * 256 + h * 128);
      const int hb = h * 128;
      float a0 = 0, a1 = 0, a2 = 0, a3 = 0;
#pragma unroll 8
      for (int j = 0; j < 32; ++j) {
        float4 wv = w4[j];
        float4 v0 = *(const float4*)&sg[0][hb + 4 * j];
        float4 v1 = *(const float4*)&sg[1][hb + 4 * j];
        float4 v2 = *(const float4*)&sg[2][hb + 4 * j];
        float4 v3 = *(const float4*)&sg[3][hb + 4 * j];
        a0 += v0.x * wv.x + v0.y * wv.y + v0.z * wv.z + v0.w * wv.w;
        a1 += v1.x * wv.x + v1.y * wv.y + v1.z * wv.z + v1.w * wv.w;
        a2 += v2.x * wv.x + v2.y * wv.y + v2.z * wv.z + v2.w * wv.w;
        a3 += v3.x * wv.x + v3.y * wv.y + v3.z * wv.z + v3.w * wv.w;
      }
      red[h][0][tt] = a0; red[h][1][tt] = a1; red[h][2][tt] = a2; red[h][3][tt] = a3;
    }
    __syncthreads();
    if (h == 0) {
#pragma unroll
      for (int p = 0; p < 4; ++p)
        H[(size_t)(NOBJ + p0 + p) * DD + tt] = red[0][p][tt] + red[1][p][tt];
    }
  } else {
    // ---- emb2: 16 blocks x 2 rows (h = local row) + H_obj fusion ----
    const int r = (b - NP / 4) * 2 + h;   // 0..31
    float s[8];
#pragma unroll
    for (int u = 0; u < 8; ++u) s[u] = 0.f;
#pragma unroll
    for (int c0 = 0; c0 < CH; c0 += 8) {
#pragma unroll
      for (int u = 0; u < 8; ++u)
        s[u] += part[(size_t)(c0 + u) * (NOBJ * DD) + r * DD + tt];
    }
    float tot = ((s[0] + s[1]) + (s[2] + s[3])) + ((s[4] + s[5]) + (s[6] + s[7]));
    h2[h][tt] = fmaxf(tot + b1[tt], 0.f);
    __syncthreads();
    // W2 GEMM (full K per thread)
    {
      const float4* w4 = (const float4*)(W2T + (size_t)tt * DD);
      const float* hp = &h2[h][0];
      float a0 = 0, a1 = 0, a2 = 0, a3 = 0;
#pragma unroll 8
      for (int j = 0; j < 64; ++j) {
        float4 wv = w4[j];
        float4 hv = *(const float4*)&hp[4 * j];
        a0 += hv.x * wv.x; a1 += hv.y * wv.y; a2 += hv.z * wv.z; a3 += hv.w * wv.w;
      }
      float v = (a0 + a1) + (a2 + a3) + b2[tt];
      objf[r * DD + tt] = v;
      sg[h][tt] = v;
    }
    __syncthreads();
    // H_obj = objf @ Wg
    {
      const float4* w4 = (const float4*)(WgT + (size_t)tt * DD);
      const float* hp = &sg[h][0];
      float a0 = 0, a1 = 0, a2 = 0, a3 = 0;
#pragma unroll 8
      for (int j = 0; j < 64; ++j) {
        float4 wv = w4[j];
        float4 hv = *(const float4*)&hp[4 * j];
        a0 += hv.x * wv.x; a1 += hv.y * wv.y; a2 += hv.z * wv.z; a3 += hv.w * wv.w;
      }
      H[(size_t)r * DD + tt] = (a0 + a1) + (a2 + a3);
    }
  }
}

// ============ K_HEADS: rel(0..247, 4 pairs) + obj(248..279), 1024 thr ======
__global__ void __launch_bounds__(1024, 1)
k_heads(const float* __restrict__ H, const float* __restrict__ objf,
        const float* __restrict__ relf, const int* __restrict__ pairs,
        const float* __restrict__ bg,
        const float* __restrict__ WopT, const float* __restrict__ bop,
        const float* __restrict__ WrpT, const float* __restrict__ brp,
        float* __restrict__ out) {
  const int b = blockIdx.x, t = threadIdx.x;
  const int p = t >> 8, tt = t & 255;
  if (b < NP / 4) {
    __shared__ __align__(16) float gr[4][DD];
    __shared__ float red[4][4][64];
    const int r = b * 4 + p;
    int si = pairs[2 * r], oi = pairs[2 * r + 1];
    float hsum = H[si * DD + tt] + H[oi * DD + tt] + H[(size_t)(NOBJ + r) * DD + tt];
    gr[p][tt] = fmaxf(hsum * (1.f / 3.f) + bg[tt], 0.f) + relf[(size_t)r * DD + tt];
    __syncthreads();
    const int q = tt >> 6, c = tt & 63;
    float a = 0.f;
    if (c < RC) {
      const float4* w4 = (const float4*)(WrpT + c * 256 + q * 64);
#pragma unroll
      for (int j = 0; j < 16; ++j) {
        float4 wv = w4[j];
        float4 gv = *(const float4*)&gr[p][q * 64 + 4 * j];
        a += gv.x * wv.x + gv.y * wv.y + gv.z * wv.z + gv.w * wv.w;
      }
    }
    red[p][q][c] = a;
    __syncthreads();
    if (tt < RC)
      out[NOBJ * OC + (size_t)r * RC + tt] =
          red[p][0][tt] + red[p][1][tt] + red[p][2][tt] + red[p][3][tt] + brp[tt];
  } else {
    const int i = b - NP / 4;   // 0..31
    const int slice = p;
    __shared__ int2 pr[NP];
    __shared__ float red2[4][DD];
    __shared__ __align__(16) float gro[DD];
    const int2* p2 = (const int2*)pairs;
    for (int r = t; r < NP; r += 1024) pr[r] = p2[r];
    __syncthreads();
    float acc = 0.f;
    if (slice == 0) {
#pragma unroll 8
      for (int j = 0; j < NOBJ; ++j) acc += H[j * DD + tt];
    }
    const int rbeg = slice * 248;
#pragma unroll 8
    for (int r = rbeg; r < rbeg + 248; ++r) {
      int2 q = pr[r];
      float v = H[(size_t)(NOBJ + r) * DD + tt];
      if (q.x == i || q.y == i) acc += v;
    }
    red2[slice][tt] = acc;
    __syncthreads();
    if (t < DD) {
      float pre = (red2[0][t] + red2[1][t] + red2[2][t] + red2[3][t]) * (1.f / 94.f);
      gro[t] = fmaxf(pre + bg[t], 0.f) + objf[i * DD + t];
    }
    __syncthreads();
    float hsum = 0.f;
    if (tt < OC) {
      const float4* w4 = (const float4*)(WopT + tt * 256 + slice * 64);
#pragma unroll
      for (int j = 0; j < 16; ++j) {
        float4 wv = w4[j];
        float4 gv = *(const float4*)&gro[slice * 64 + 4 * j];
        hsum += gv.x * wv.x + gv.y * wv.y + gv.z * wv.z + gv.w * wv.w;
      }
    }
    red2[slice][tt] = hsum;
    __syncthreads();
    if (t < OC)
      out[i * OC + t] = red2[0][t] + red2[1][t] + red2[2][t] + red2[3][t] + bop[t];
  }
}

extern "C" void kernel_launch(void* const* d_in, const int* in_sizes, int n_in,
                              void* d_out, int out_size, void* d_ws, size_t ws_size,
                              hipStream_t stream) {
  const float* roi   = (const float*)d_in[0];
  const float* bbox  = (const float*)d_in[1];
  const float* logit = (const float*)d_in[2];
  const float* uf    = (const float*)d_in[3];
  const int*   pairs = (const int*)d_in[4];
  const float* W1    = (const float*)d_in[5];
  const float* b1    = (const float*)d_in[6];
  const float* W2    = (const float*)d_in[7];
  const float* b2    = (const float*)d_in[8];
  const float* fc1w  = (const float*)d_in[9];
  const float* fc1b  = (const float*)d_in[10];
  const float* fc2w  = (const float*)d_in[11];
  const float* fc2b  = (const float*)d_in[12];
  const float* Wc1   = (const float*)d_in[13];
  const float* bc1   = (const float*)d_in[14];
  const float* Wc2   = (const float*)d_in[15];
  const float* bc2   = (const float*)d_in[16];
  const float* Wg    = (const float*)d_in[17];
  const float* bg    = (const float*)d_in[18];
  const float* Wop   = (const float*)d_in[19];
  const float* bop   = (const float*)d_in[20];
  const float* Wrp   = (const float*)d_in[21];
  const float* brp   = (const float*)d_in[22];

  float* ws    = (float*)d_ws;
  float* part  = ws + OFF_PART;
  float* objf  = ws + OFF_OBJF;
  float* sAll  = ws + OFF_SALL;
  float* relf  = ws + OFF_RELF;
  float* Hbuf  = ws + OFF_H;
  float* W2T   = ws + OFF_W2T;
  float* Wc1T  = ws + OFF_WC1T;
  float* Wc2T  = ws + OFF_WC2T;
  float* WgT   = ws + OFF_WGT;
  float* f1wT  = ws + OFF_FC1WT;
  float* f2wT  = ws + OFF_FC2WT;
  float* WopT  = ws + OFF_WOPT;
  float* WrpT  = ws + OFF_WRPT;
  float* out   = (float*)d_out;

  k_pre<<<NP + CH + 256, 256, 0, stream>>>(uf, bbox, pairs, roi, logit, W1,
                                           W2, Wc1, Wc2, Wg, fc1w, fc2w, Wop, Wrp,
                                           sAll, part, W2T, Wc1T, Wc2T, WgT,
                                           f1wT, f2wT, WopT, WrpT);
  k_mid2<<<NP / 4 + 16, 512, 0, stream>>>(sAll, f1wT, fc1b, f2wT, fc2b,
                                          Wc1T, bc1, Wc2T, bc2, WgT,
                                          part, b1, W2T, b2, relf, objf, Hbuf);
  k_heads<<<NP / 4 + NOBJ, 1024, 0, stream>>>(Hbuf, objf, relf, pairs, bg,
                                              WopT, bop, WrpT, brp, out);
}

// Round 5
// 521.332 us; speedup vs baseline: 1.1712x; 1.0088x over previous
//
#include <hip/hip_runtime.h>
#include <cstdint>
#include <cstddef>

#define NOBJ 32
#define NP   992
#define DD   256
#define SP   196   // 14*14
#define OC   151
#define RC   51
#define RED  64
#define KIN  4251  // 4096 + 151 + 4
#define CH   128   // emb1 k-chunks
#define KPC  34    // ceil(4251/128)

// ---- ws layout (float offsets) ----
#define OFF_PART   0u         // 128*32*256 = 1048576
#define OFF_OBJF   1048576u   // 8192
#define OFF_SALL   1056768u   // 992*768 = 761856
#define OFF_RELF   1818624u   // 253952
#define OFF_H      2072576u   // 262144
#define OFF_W2T    2334720u   // 65536
#define OFF_WC1T   2400256u   // 196608
#define OFF_WC2T   2596864u   // 65536
#define OFF_WGT    2662400u   // 65536
#define OFF_FC1WT  2727936u   // 49152
#define OFF_FC2WT  2777088u   // 49152
#define OFF_WOPT   2826240u   // 38656
#define OFF_WRPT   2864896u   // 13056

#define TR_TOT 543232  // total transposed elements

// ============ K_PRE: union(0..991) + emb1(992..1119) + transpose(1120..1375)
__global__ void k_pre(const float* __restrict__ uf,
                      const float* __restrict__ bbox,
                      const int* __restrict__ pairs,
                      const float* __restrict__ roi,
                      const float* __restrict__ logits,
                      const float* __restrict__ W1,
                      const float* __restrict__ W2,  const float* __restrict__ Wc1,
                      const float* __restrict__ Wc2, const float* __restrict__ Wg,
                      const float* __restrict__ f1w, const float* __restrict__ f2w,
                      const float* __restrict__ Wop, const float* __restrict__ Wrp,
                      float* __restrict__ sAll, float* __restrict__ part,
                      float* __restrict__ W2T,  float* __restrict__ Wc1T,
                      float* __restrict__ Wc2T, float* __restrict__ WgT,
                      float* __restrict__ f1wT, float* __restrict__ f2wT,
                      float* __restrict__ WopT, float* __restrict__ WrpT) {
  const int b = blockIdx.x, t = threadIdx.x;
  if (b < NP) {
    // ---- union masked means: coalesced LDS-tiled version ----
    const int p = b;
    __shared__ __align__(16) float tile[64 * SP + 64];  // 49 KB + slack
    __shared__ __align__(16) float wS[256];
    __shared__ __align__(16) float wO[256];
    __shared__ __align__(16) float wB[256];
    __shared__ float pacc[3][4][64];
    if (t < SP) {
      int si = pairs[2 * p], oi = pairs[2 * p + 1];
      float sx1 = bbox[si * 4 + 0], sy1 = bbox[si * 4 + 1];
      float sx2 = bbox[si * 4 + 2], sy2 = bbox[si * 4 + 3];
      float ox1 = bbox[oi * 4 + 0], oy1 = bbox[oi * 4 + 1];
      float ox2 = bbox[oi * 4 + 2], oy2 = bbox[oi * 4 + 3];
      float ux = fminf(sx1, ox1), uy = fminf(sy1, oy1);
      float xr = 14.f / fmaxf(sx2 - ux, ox2 - ux);
      float yr = 14.f / fmaxf(sy2 - uy, oy2 - uy);
      float xs0 = rintf((sx1 - ux) * xr), xs1 = rintf((sx2 - ux) * xr);
      float xo0 = rintf((ox1 - ux) * xr), xo1 = rintf((ox2 - ux) * xr);
      float ys0 = rintf((sy1 - uy) * yr), ys1 = rintf((sy2 - uy) * yr);
      float yo0 = rintf((oy1 - uy) * yr), yo1 = rintf((oy2 - uy) * yr);
      int a = t / 14, bb = t - a * 14;
      float fa = (float)a, fb = (float)bb;
      float sm = (fa >= xs0 && fa < xs1 && fb >= ys0 && fb < ys1) ? 1.f : 0.f;
      float om = (fa >= xo0 && fa < xo1 && fb >= yo0 && fb < yo1) ? 1.f : 0.f;
      float bm = fminf(fmaxf(1.f - sm - om, 0.f), 1.f);
      wS[t] = sm; wO[t] = om; wB[t] = bm;
    } else {
      wS[t] = 0.f; wO[t] = 0.f; wB[t] = 0.f;   // zero tail for branch-free loop
    }
    if (t < 64) tile[64 * SP + t] = 0.f;       // zero slack (hit by c=63,q=3 overrun)
    __syncthreads();
    const int c = t >> 2, q = t & 3;           // channel-in-tile, s-quarter
    const float* row = tile + c * SP + q * 52;
    const float* mS = wS + q * 52;
    const float* mO = wO + q * 52;
    const float* mB = wB + q * 52;
    const float inv = 1.f / 196.f;
#pragma unroll 1
    for (int ti = 0; ti < 4; ++ti) {
      // stage 64 channels (49 KB) coalesced: LDS layout == global layout
      const float4* src4 = (const float4*)(uf + (size_t)p * (DD * SP) + ti * (64 * SP));
      float4* dst4 = (float4*)tile;
      for (int f = t; f < 64 * SP / 4; f += 256) dst4[f] = src4[f];
      __syncthreads();
      float a0 = 0.f, a1 = 0.f, a2 = 0.f;
#pragma unroll
      for (int g = 0; g < 13; ++g) {           // 13*4=52 cols (q=3 tail masked by 0)
        float4 v  = *(const float4*)&row[4 * g];
        float4 ms = *(const float4*)&mS[4 * g];
        float4 mo = *(const float4*)&mO[4 * g];
        float4 mb = *(const float4*)&mB[4 * g];
        a0 += v.x * ms.x + v.y * ms.y + v.z * ms.z + v.w * ms.w;
        a1 += v.x * mo.x + v.y * mo.y + v.z * mo.z + v.w * mo.w;
        a2 += v.x * mb.x + v.y * mb.y + v.z * mb.z + v.w * mb.w;
      }
      pacc[0][q][c] = a0; pacc[1][q][c] = a1; pacc[2][q][c] = a2;
      __syncthreads();
      if (t < 192) {
        int m = t >> 6, c2 = t & 63;
        float s = pacc[m][0][c2] + pacc[m][1][c2] + pacc[m][2][c2] + pacc[m][3][c2];
        sAll[(size_t)p * 768 + m * 256 + ti * 64 + c2] = s * inv;
      }
      __syncthreads();                         // before next tile overwrite
    }
  } else if (b < NP + CH) {
    // ---- emb1 split-K partial ----
    const int chunk = b - NP;
    int k0 = chunk * KPC;
    int k1 = k0 + KPC; if (k1 > KIN) k1 = KIN;
    float acc[NOBJ];
#pragma unroll
    for (int i = 0; i < NOBJ; ++i) acc[i] = 0.f;
#pragma unroll 2
    for (int k = k0; k < k1; ++k) {
      float w = W1[(size_t)k * DD + t];
      const float* xp; int stride;
      if (k < 4096)            { xp = roi    + k;               stride = 4096; }
      else if (k < 4096 + OC)  { xp = logits + (k - 4096);      stride = OC;   }
      else                     { xp = bbox   + (k - 4096 - OC); stride = 4;    }
#pragma unroll
      for (int i = 0; i < NOBJ; ++i) { acc[i] += xp[0] * w; xp += stride; }
    }
    float* pout = part + (size_t)chunk * (NOBJ * DD) + t;
#pragma unroll
    for (int i = 0; i < NOBJ; ++i) pout[i * DD] = acc[i];
  } else {
    // ---- weight transposes: coalesced writes, strided (L2-hit) reads ----
    for (int o = (b - NP - CH) * 256 + t; o < TR_TOT; o += 256 * 256) {
      float v; float* dst;
      if (o < 65536)       { int q = o;          v = W2 [(q & 255) * 256 + (q >> 8)]; dst = W2T  + q; }
      else if (o < 262144) { int q = o - 65536;  int c = q / 768, k = q - c * 768;
                             v = Wc1[k * 256 + c];                                    dst = Wc1T + q; }
      else if (o < 327680) { int q = o - 262144; v = Wc2[(q & 255) * 256 + (q >> 8)]; dst = Wc2T + q; }
      else if (o < 393216) { int q = o - 327680; v = Wg [(q & 255) * 256 + (q >> 8)]; dst = WgT  + q; }
      else if (o < 442368) { int q = o - 393216;
                             v = f1w[(q >> 14) * 16384 + (q & 255) * 64 + ((q >> 8) & 63)];
                             dst = f1wT + q; }
      else if (o < 491520) { int q = o - 442368;
                             v = f2w[(q >> 14) * 16384 + (q & 63) * 256 + ((q >> 6) & 255)];
                             dst = f2wT + q; }
      else if (o < 530176) { int q = o - 491520; v = Wop[(q & 255) * OC + (q >> 8)];  dst = WopT + q; }
      else                 { int q = o - 530176; v = Wrp[(q & 255) * RC + (q >> 8)];  dst = WrpT + q; }
      *dst = v;
    }
  }
}

// ============ K_MID2: attrel w/ K-split x2 + H fusion; emb2 + H fusion =====
__global__ void __launch_bounds__(512, 1)
k_mid2(const float* __restrict__ sAll,
       const float* __restrict__ f1wT, const float* __restrict__ f1b,
       const float* __restrict__ f2wT, const float* __restrict__ f2b,
       const float* __restrict__ Wc1T, const float* __restrict__ bc1,
       const float* __restrict__ Wc2T, const float* __restrict__ bc2,
       const float* __restrict__ WgT,
       const float* __restrict__ part, const float* __restrict__ b1,
       const float* __restrict__ W2T,  const float* __restrict__ b2,
       float* __restrict__ relf, float* __restrict__ objf,
       float* __restrict__ H) {
  const int b = blockIdx.x, t = threadIdx.x;
  const int h = t >> 8, tt = t & 255;
  __shared__ __align__(16) float sg[4][768];
  __shared__ __align__(16) float ha[4][192];
  __shared__ __align__(16) float h2[4][256];
  __shared__ __align__(16) float red[2][4][256];
  if (b < NP / 4) {
    const int p0 = b * 4;
    {
      const float4* src = (const float4*)(sAll + (size_t)p0 * 768);
      float4* dst = (float4*)&sg[0][0];
      for (int j = t; j < 768; j += 512) dst[j] = src[j];
    }
    __syncthreads();
    // ---- P1: fc1 (cols tt<192, K=256 split 128 by h) ----
    if (tt < 192) {
      const float4* w4 = (const float4*)(f1wT + tt * 256 + h * 128);
      const int sb = (tt >> 6) * 256 + h * 128;
      float a0 = 0, a1 = 0, a2 = 0, a3 = 0;
#pragma unroll 8
      for (int j = 0; j < 32; ++j) {
        float4 wv = w4[j];
        float4 s0 = *(const float4*)&sg[0][sb + 4 * j];
        float4 s1 = *(const float4*)&sg[1][sb + 4 * j];
        float4 s2 = *(const float4*)&sg[2][sb + 4 * j];
        float4 s3 = *(const float4*)&sg[3][sb + 4 * j];
        a0 += s0.x * wv.x + s0.y * wv.y + s0.z * wv.z + s0.w * wv.w;
        a1 += s1.x * wv.x + s1.y * wv.y + s1.z * wv.z + s1.w * wv.w;
        a2 += s2.x * wv.x + s2.y * wv.y + s2.z * wv.z + s2.w * wv.w;
        a3 += s3.x * wv.x + s3.y * wv.y + s3.z * wv.z + s3.w * wv.w;
      }
      red[h][0][tt] = a0; red[h][1][tt] = a1; red[h][2][tt] = a2; red[h][3][tt] = a3;
    }
    __syncthreads();
    if (h == 0 && tt < 192) {
      float bb = f1b[tt];
#pragma unroll
      for (int p = 0; p < 4; ++p)
        ha[p][tt] = fmaxf(red[0][p][tt] + red[1][p][tt] + bb, 0.f);
    }
    __syncthreads();
    // ---- P2: fc2 + sigmoid gate ----
    for (int br = 0; br < 3; ++br) {
      const float4* w4 = (const float4*)(f2wT + br * 16384 + tt * 64 + h * 32);
      const int hb = br * 64 + h * 32;
      float a0 = 0, a1 = 0, a2 = 0, a3 = 0;
#pragma unroll
      for (int j = 0; j < 8; ++j) {
        float4 wv = w4[j];
        float4 v0 = *(const float4*)&ha[0][hb + 4 * j];
        float4 v1 = *(const float4*)&ha[1][hb + 4 * j];
        float4 v2 = *(const float4*)&ha[2][hb + 4 * j];
        float4 v3 = *(const float4*)&ha[3][hb + 4 * j];
        a0 += v0.x * wv.x + v0.y * wv.y + v0.z * wv.z + v0.w * wv.w;
        a1 += v1.x * wv.x + v1.y * wv.y + v1.z * wv.z + v1.w * wv.w;
        a2 += v2.x * wv.x + v2.y * wv.y + v2.z * wv.z + v2.w * wv.w;
        a3 += v3.x * wv.x + v3.y * wv.y + v3.z * wv.z + v3.w * wv.w;
      }
      red[h][0][tt] = a0; red[h][1][tt] = a1; red[h][2][tt] = a2; red[h][3][tt] = a3;
      __syncthreads();
      if (h == 0) {
        float bb = f2b[br * 256 + tt];
#pragma unroll
        for (int p = 0; p < 4; ++p) {
          float g = 1.f / (1.f + expf(-(red[0][p][tt] + red[1][p][tt] + bb)));
          sg[p][br * 256 + tt] *= g;
        }
      }
      __syncthreads();
    }
    // ---- P3: rel fc1 768->256 relu ----
    {
      const float4* w4 = (const float4*)(Wc1T + (size_t)tt * 768 + h * 384);
      const int gb = h * 384;
      float a0 = 0, a1 = 0, a2 = 0, a3 = 0;
#pragma unroll 8
      for (int j = 0; j < 96; ++j) {
        float4 wv = w4[j];
        float4 g0 = *(const float4*)&sg[0][gb + 4 * j];
        float4 g1 = *(const float4*)&sg[1][gb + 4 * j];
        float4 g2 = *(const float4*)&sg[2][gb + 4 * j];
        float4 g3 = *(const float4*)&sg[3][gb + 4 * j];
        a0 += g0.x * wv.x + g0.y * wv.y + g0.z * wv.z + g0.w * wv.w;
        a1 += g1.x * wv.x + g1.y * wv.y + g1.z * wv.z + g1.w * wv.w;
        a2 += g2.x * wv.x + g2.y * wv.y + g2.z * wv.z + g2.w * wv.w;
        a3 += g3.x * wv.x + g3.y * wv.y + g3.z * wv.z + g3.w * wv.w;
      }
      red[h][0][tt] = a0; red[h][1][tt] = a1; red[h][2][tt] = a2; red[h][3][tt] = a3;
    }
    __syncthreads();
    if (h == 0) {
      float bb = bc1[tt];
#pragma unroll
      for (int p = 0; p < 4; ++p)
        h2[p][tt] = fmaxf(red[0][p][tt] + red[1][p][tt] + bb, 0.f);
    }
    __syncthreads();
    // ---- P4: rel fc2 -> relf + stash ----
    {
      const float4* w4 = (const float4*)(Wc2T + (size_t)tt * 256 + h * 128);
      const int hb = h * 128;
      float a0 = 0, a1 = 0, a2 = 0, a3 = 0;
#pragma unroll 8
      for (int j = 0; j < 32; ++j) {
        float4 wv = w4[j];
        float4 v0 = *(const float4*)&h2[0][hb + 4 * j];
        float4 v1 = *(const float4*)&h2[1][hb + 4 * j];
        float4 v2 = *(const float4*)&h2[2][hb + 4 * j];
        float4 v3 = *(const float4*)&h2[3][hb + 4 * j];
        a0 += v0.x * wv.x + v0.y * wv.y + v0.z * wv.z + v0.w * wv.w;
        a1 += v1.x * wv.x + v1.y * wv.y + v1.z * wv.z + v1.w * wv.w;
        a2 += v2.x * wv.x + v2.y * wv.y + v2.z * wv.z + v2.w * wv.w;
        a3 += v3.x * wv.x + v3.y * wv.y + v3.z * wv.z + v3.w * wv.w;
      }
      red[h][0][tt] = a0; red[h][1][tt] = a1; red[h][2][tt] = a2; red[h][3][tt] = a3;
    }
    __syncthreads();
    if (h == 0) {
      float bb = bc2[tt];
#pragma unroll
      for (int p = 0; p < 4; ++p) {
        float v = red[0][p][tt] + red[1][p][tt] + bb;
        relf[(size_t)(p0 + p) * DD + tt] = v;
        sg[p][tt] = v;
      }
    }
    __syncthreads();
    // ---- P5: H_rel = relf @ Wg ----
    {
      const float4* w4 = (const float4*)(WgT + (size_t)tt * 256 + h * 128);
      const int hb = h * 128;
      float a0 = 0, a1 = 0, a2 = 0, a3 = 0;
#pragma unroll 8
      for (int j = 0; j < 32; ++j) {
        float4 wv = w4[j];
        float4 v0 = *(const float4*)&sg[0][hb + 4 * j];
        float4 v1 = *(const float4*)&sg[1][hb + 4 * j];
        float4 v2 = *(const float4*)&sg[2][hb + 4 * j];
        float4 v3 = *(const float4*)&sg[3][hb + 4 * j];
        a0 += v0.x * wv.x + v0.y * wv.y + v0.z * wv.z + v0.w * wv.w;
        a1 += v1.x * wv.x + v1.y * wv.y + v1.z * wv.z + v1.w * wv.w;
        a2 += v2.x * wv.x + v2.y * wv.y + v2.z * wv.z + v2.w * wv.w;
        a3 += v3.x * wv.x + v3.y * wv.y + v3.z * wv.z + v3.w * wv.w;
      }
      red[h][0][tt] = a0; red[h][1][tt] = a1; red[h][2][tt] = a2; red[h][3][tt] = a3;
    }
    __syncthreads();
    if (h == 0) {
#pragma unroll
      for (int p = 0; p < 4; ++p)
        H[(size_t)(NOBJ + p0 + p) * DD + tt] = red[0][p][tt] + red[1][p][tt];
    }
  } else {
    // ---- emb2 + H_obj ----
    const int r = (b - NP / 4) * 2 + h;   // 0..31
    float s[8];
#pragma unroll
    for (int u = 0; u < 8; ++u) s[u] = 0.f;
#pragma unroll
    for (int c0 = 0; c0 < CH; c0 += 8) {
#pragma unroll
      for (int u = 0; u < 8; ++u)
        s[u] += part[(size_t)(c0 + u) * (NOBJ * DD) + r * DD + tt];
    }
    float tot = ((s[0] + s[1]) + (s[2] + s[3])) + ((s[4] + s[5]) + (s[6] + s[7]));
    h2[h][tt] = fmaxf(tot + b1[tt], 0.f);
    __syncthreads();
    {
      const float4* w4 = (const float4*)(W2T + (size_t)tt * DD);
      const float* hp = &h2[h][0];
      float a0 = 0, a1 = 0, a2 = 0, a3 = 0;
#pragma unroll 8
      for (int j = 0; j < 64; ++j) {
        float4 wv = w4[j];
        float4 hv = *(const float4*)&hp[4 * j];
        a0 += hv.x * wv.x; a1 += hv.y * wv.y; a2 += hv.z * wv.z; a3 += hv.w * wv.w;
      }
      float v = (a0 + a1) + (a2 + a3) + b2[tt];
      objf[r * DD + tt] = v;
      sg[h][tt] = v;
    }
    __syncthreads();
    {
      const float4* w4 = (const float4*)(WgT + (size_t)tt * DD);
      const float* hp = &sg[h][0];
      float a0 = 0, a1 = 0, a2 = 0, a3 = 0;
#pragma unroll 8
      for (int j = 0; j < 64; ++j) {
        float4 wv = w4[j];
        float4 hv = *(const float4*)&hp[4 * j];
        a0 += hv.x * wv.x; a1 += hv.y * wv.y; a2 += hv.z * wv.z; a3 += hv.w * wv.w;
      }
      H[(size_t)r * DD + tt] = (a0 + a1) + (a2 + a3);
    }
  }
}

// ============ K_HEADS: rel(0..247, 4 pairs) + obj(248..279), 1024 thr ======
__global__ void __launch_bounds__(1024, 1)
k_heads(const float* __restrict__ H, const float* __restrict__ objf,
        const float* __restrict__ relf, const int* __restrict__ pairs,
        const float* __restrict__ bg,
        const float* __restrict__ WopT, const float* __restrict__ bop,
        const float* __restrict__ WrpT, const float* __restrict__ brp,
        float* __restrict__ out) {
  const int b = blockIdx.x, t = threadIdx.x;
  const int p = t >> 8, tt = t & 255;
  if (b < NP / 4) {
    __shared__ __align__(16) float gr[4][DD];
    __shared__ float red[4][4][64];
    const int r = b * 4 + p;
    int si = pairs[2 * r], oi = pairs[2 * r + 1];
    float hsum = H[si * DD + tt] + H[oi * DD + tt] + H[(size_t)(NOBJ + r) * DD + tt];
    gr[p][tt] = fmaxf(hsum * (1.f / 3.f) + bg[tt], 0.f) + relf[(size_t)r * DD + tt];
    __syncthreads();
    const int q = tt >> 6, c = tt & 63;
    float a = 0.f;
    if (c < RC) {
      const float4* w4 = (const float4*)(WrpT + c * 256 + q * 64);
#pragma unroll
      for (int j = 0; j < 16; ++j) {
        float4 wv = w4[j];
        float4 gv = *(const float4*)&gr[p][q * 64 + 4 * j];
        a += gv.x * wv.x + gv.y * wv.y + gv.z * wv.z + gv.w * wv.w;
      }
    }
    red[p][q][c] = a;
    __syncthreads();
    if (tt < RC)
      out[NOBJ * OC + (size_t)r * RC + tt] =
          red[p][0][tt] + red[p][1][tt] + red[p][2][tt] + red[p][3][tt] + brp[tt];
  } else {
    const int i = b - NP / 4;   // 0..31
    const int slice = p;
    __shared__ int2 pr[NP];
    __shared__ float red2[4][DD];
    __shared__ __align__(16) float gro[DD];
    const int2* p2 = (const int2*)pairs;
    for (int r = t; r < NP; r += 1024) pr[r] = p2[r];
    __syncthreads();
    float acc = 0.f;
    if (slice == 0) {
#pragma unroll 8
      for (int j = 0; j < NOBJ; ++j) acc += H[j * DD + tt];
    }
    const int rbeg = slice * 248;
#pragma unroll 8
    for (int r = rbeg; r < rbeg + 248; ++r) {
      int2 q = pr[r];
      float v = H[(size_t)(NOBJ + r) * DD + tt];
      if (q.x == i || q.y == i) acc += v;
    }
    red2[slice][tt] = acc;
    __syncthreads();
    if (t < DD) {
      float pre = (red2[0][t] + red2[1][t] + red2[2][t] + red2[3][t]) * (1.f / 94.f);
      gro[t] = fmaxf(pre + bg[t], 0.f) + objf[i * DD + t];
    }
    __syncthreads();
    float hsum = 0.f;
    if (tt < OC) {
      const float4* w4 = (const float4*)(WopT + tt * 256 + slice * 64);
#pragma unroll
      for (int j = 0; j < 16; ++j) {
        float4 wv = w4[j];
        float4 gv = *(const float4*)&gro[slice * 64 + 4 * j];
        hsum += gv.x * wv.x + gv.y * wv.y + gv.z * wv.z + gv.w * wv.w;
      }
    }
    red2[slice][tt] = hsum;
    __syncthreads();
    if (t < OC)
      out[i * OC + t] = red2[0][t] + red2[1][t] + red2[2][t] + red2[3][t] + bop[t];
  }
}

extern "C" void kernel_launch(void* const* d_in, const int* in_sizes, int n_in,
                              void* d_out, int out_size, void* d_ws, size_t ws_size,
                              hipStream_t stream) {
  const float* roi   = (const float*)d_in[0];
  const float* bbox  = (const float*)d_in[1];
  const float* logit = (const float*)d_in[2];
  const float* uf    = (const float*)d_in[3];
  const int*   pairs = (const int*)d_in[4];
  const float* W1    = (const float*)d_in[5];
  const float* b1    = (const float*)d_in[6];
  const float* W2    = (const float*)d_in[7];
  const float* b2    = (const float*)d_in[8];
  const float* fc1w  = (const float*)d_in[9];
  const float* fc1b  = (const float*)d_in[10];
  const float* fc2w  = (const float*)d_in[11];
  const float* fc2b  = (const float*)d_in[12];
  const float* Wc1   = (const float*)d_in[13];
  const float* bc1   = (const float*)d_in[14];
  const float* Wc2   = (const float*)d_in[15];
  const float* bc2   = (const float*)d_in[16];
  const float* Wg    = (const float*)d_in[17];
  const float* bg    = (const float*)d_in[18];
  const float* Wop   = (const float*)d_in[19];
  const float* bop   = (const float*)d_in[20];
  const float* Wrp   = (const float*)d_in[21];
  const float* brp   = (const float*)d_in[22];

  float* ws    = (float*)d_ws;
  float* part  = ws + OFF_PART;
  float* objf  = ws + OFF_OBJF;
  float* sAll  = ws + OFF_SALL;
  float* relf  = ws + OFF_RELF;
  float* Hbuf  = ws + OFF_H;
  float* W2T   = ws + OFF_W2T;
  float* Wc1T  = ws + OFF_WC1T;
  float* Wc2T  = ws + OFF_WC2T;
  float* WgT   = ws + OFF_WGT;
  float* f1wT  = ws + OFF_FC1WT;
  float* f2wT  = ws + OFF_FC2WT;
  float* WopT  = ws + OFF_WOPT;
  float* WrpT  = ws + OFF_WRPT;
  float* out   = (float*)d_out;

  k_pre<<<NP + CH + 256, 256, 0, stream>>>(uf, bbox, pairs, roi, logit, W1,
                                           W2, Wc1, Wc2, Wg, fc1w, fc2w, Wop, Wrp,
                                           sAll, part, W2T, Wc1T, Wc2T, WgT,
                                           f1wT, f2wT, WopT, WrpT);
  k_mid2<<<NP / 4 + 16, 512, 0, stream>>>(sAll, f1wT, fc1b, f2wT, fc2b,
                                          Wc1T, bc1, Wc2T, bc2, WgT,
                                          part, b1, W2T, b2, relf, objf, Hbuf);
  k_heads<<<NP / 4 + NOBJ, 1024, 0, stream>>>(Hbuf, objf, relf, pairs, bg,
                                              WopT, bop, WrpT, brp, out);
}